// Round 1
// baseline (296.055 us; speedup 1.0000x reference)
//
#include <hip/hip_runtime.h>
#include <math.h>

#define B_ 16
#define T_ 2048
#define H_ 1024
#define TPB 8  // t-rows per block in k1

// ---------------------------------------------------------------------------
// K1: alphas[b,t] = sigmoid( sum_h relu(conv(h,t) + conv_b + hidden) * lin_w + lin_b )
// conv(h,t) = w0[h]*hidden[b,t-1,h] + w1[h]*hidden[b,t,h] + w2[h]*hidden[b,t+1,h]
// Block = 256 threads, each owns 4 h's (float4); processes TPB consecutive t
// with rolling prev/curr/next rows so each hidden row is loaded ~1.25x.
// ---------------------------------------------------------------------------
__global__ __launch_bounds__(256) void k1_alphas(
    const float* __restrict__ hidden, const float* __restrict__ conv_w,
    const float* __restrict__ conv_b, const float* __restrict__ lin_w,
    const float* __restrict__ lin_b, float* __restrict__ alphas)
{
    const int tile = blockIdx.x & (T_ / TPB - 1);
    const int b    = blockIdx.x / (T_ / TPB);
    const int tid  = threadIdx.x;
    const int h0   = tid * 4;

    // conv_w layout [H][1][3]: 12 consecutive floats per thread, 16B-aligned
    float w0[4], w1[4], w2[4];
    {
        const float4* cw = (const float4*)(conv_w + (size_t)h0 * 3);
        float4 c0 = cw[0], c1 = cw[1], c2 = cw[2];
        w0[0] = c0.x; w1[0] = c0.y; w2[0] = c0.z;
        w0[1] = c0.w; w1[1] = c1.x; w2[1] = c1.y;
        w0[2] = c1.z; w1[2] = c1.w; w2[2] = c2.x;
        w0[3] = c2.y; w1[3] = c2.z; w2[3] = c2.w;
    }
    const float4 cb = *(const float4*)(conv_b + h0);
    const float4 lw = *(const float4*)(lin_w + h0);
    const float  lb = lin_b[0];

    const size_t base = ((size_t)b * T_) * H_ + h0;
    const int t0 = tile * TPB;

    float4 prev = (t0 > 0) ? *(const float4*)(hidden + base + (size_t)(t0 - 1) * H_)
                           : make_float4(0.f, 0.f, 0.f, 0.f);
    float4 curr = *(const float4*)(hidden + base + (size_t)t0 * H_);
    float4 next;

    __shared__ float lds[4][TPB];
    const int wave = tid >> 6;
    const int lane = tid & 63;

    #pragma unroll
    for (int tt = 0; tt < TPB; ++tt) {
        const int t = t0 + tt;
        next = (t + 1 < T_) ? *(const float4*)(hidden + base + (size_t)(t + 1) * H_)
                            : make_float4(0.f, 0.f, 0.f, 0.f);
        float p = 0.f, v;
        v = fmaf(w0[0], prev.x, fmaf(w1[0], curr.x, fmaf(w2[0], next.x, cb.x + curr.x)));
        p = fmaf(fmaxf(v, 0.f), lw.x, p);
        v = fmaf(w0[1], prev.y, fmaf(w1[1], curr.y, fmaf(w2[1], next.y, cb.y + curr.y)));
        p = fmaf(fmaxf(v, 0.f), lw.y, p);
        v = fmaf(w0[2], prev.z, fmaf(w1[2], curr.z, fmaf(w2[2], next.z, cb.z + curr.z)));
        p = fmaf(fmaxf(v, 0.f), lw.z, p);
        v = fmaf(w0[3], prev.w, fmaf(w1[3], curr.w, fmaf(w2[3], next.w, cb.w + curr.w)));
        p = fmaf(fmaxf(v, 0.f), lw.w, p);
        // 64-lane wave reduce
        #pragma unroll
        for (int m = 32; m; m >>= 1) p += __shfl_xor(p, m);
        if (lane == 0) lds[wave][tt] = p;
        prev = curr; curr = next;
    }
    __syncthreads();
    if (tid < TPB) {
        float s = lds[0][tid] + lds[1][tid] + lds[2][tid] + lds[3][tid] + lb;
        alphas[(size_t)b * T_ + t0 + tid] = 1.f / (1.f + expf(-s));
    }
}

// ---------------------------------------------------------------------------
// K2a: minimal serial integrate-and-fire chain. One wave; lane = batch.
// fires[b,t] = I_{t-1} + alpha_t (pre-subtract value) -- this is an output AND
// sufficient to reconstruct everything else in parallel (x-1 exact on [1,2)).
// ---------------------------------------------------------------------------
__global__ __launch_bounds__(64) void k2a_scan(
    const float* __restrict__ alphas, float* __restrict__ fires)
{
    const int b = threadIdx.x;
    if (b >= B_) return;
    const float* a = alphas + (size_t)b * T_;
    float* f = fires + (size_t)b * T_;
    float I = 0.f;
    float4 c0 = *(const float4*)(a);
    float4 c1 = *(const float4*)(a + 4);
    float4 n0 = make_float4(0, 0, 0, 0), n1 = n0;
    for (int t = 0; t < T_; t += 8) {
        if (t + 8 < T_) {
            n0 = *(const float4*)(a + t + 8);
            n1 = *(const float4*)(a + t + 12);
        }
        float av[8] = {c0.x, c0.y, c0.z, c0.w, c1.x, c1.y, c1.z, c1.w};
        #pragma unroll
        for (int j = 0; j < 8; ++j) {
            I += av[j];
            f[t + j] = I;
            if (I >= 1.0f) I -= 1.0f;   // exact (Sterbenz)
        }
        c0 = n0; c1 = n1;
    }
}

// ---------------------------------------------------------------------------
// K2b: parallel reconstruction of per-t coefficients + fire positions.
// One block per batch, 256 threads x 8 t's. Also cif_length (sum of alphas).
// ---------------------------------------------------------------------------
__global__ __launch_bounds__(256) void k2b_coef(
    const float* __restrict__ alphas, const float* __restrict__ fires,
    float* __restrict__ cur, float* __restrict__ rem,
    int* __restrict__ fire_pos, int* __restrict__ n_fires,
    float* __restrict__ cif_length, int Lpad)
{
    const int b = blockIdx.x;
    const int tid = threadIdx.x;
    const int t0 = tid * 8;
    const size_t base = (size_t)b * T_;

    float a[8], f[8];
    *(float4*)(a)     = *(const float4*)(alphas + base + t0);
    *(float4*)(a + 4) = *(const float4*)(alphas + base + t0 + 4);
    *(float4*)(f)     = *(const float4*)(fires + base + t0);
    *(float4*)(f + 4) = *(const float4*)(fires + base + t0 + 4);
    const float fprev = (t0 == 0) ? 0.f : fires[base + t0 - 1];

    float cu[8], re[8];
    bool fr[8];
    float asum = 0.f;
    int cnt = 0;
    #pragma unroll
    for (int j = 0; j < 8; ++j) {
        float fp = (j == 0) ? fprev : f[j - 1];
        float Iprev = (t0 == 0 && j == 0) ? 0.f : ((fp >= 1.f) ? fp - 1.f : fp);
        fr[j] = (f[j] >= 1.f);
        const float dist = 1.f - Iprev;
        cu[j] = fr[j] ? dist : a[j];
        re[j] = a[j] - cu[j];
        cnt += fr[j] ? 1 : 0;
        asum += a[j];
    }
    *(float4*)(cur + base + t0)     = *(float4*)(cu);
    *(float4*)(cur + base + t0 + 4) = *(float4*)(cu + 4);
    *(float4*)(rem + base + t0)     = *(float4*)(re);
    *(float4*)(rem + base + t0 + 4) = *(float4*)(re + 4);

    // block-wide exclusive prefix of fire counts
    const int lane = tid & 63, wave = tid >> 6;
    int inc = cnt;
    #pragma unroll
    for (int d = 1; d < 64; d <<= 1) {
        int v = __shfl_up(inc, d);
        if (lane >= d) inc += v;
    }
    __shared__ int wsum[4];
    if (lane == 63) wsum[wave] = inc;
    __syncthreads();
    int waveoff = 0;
    for (int w = 0; w < wave; ++w) waveoff += wsum[w];
    int r = waveoff + inc - cnt;  // exclusive prefix for this thread
    #pragma unroll
    for (int j = 0; j < 8; ++j) {
        if (fr[j]) {
            if (r < Lpad) fire_pos[b * Lpad + r] = t0 + j;
            ++r;
        }
    }
    if (tid == 255) n_fires[b] = waveoff + inc;

    // cif_length = sum of alphas
    float s = asum;
    #pragma unroll
    for (int m = 32; m; m >>= 1) s += __shfl_xor(s, m);
    __shared__ float wred[4];
    if (lane == 0) wred[wave] = s;
    __syncthreads();
    if (tid == 0) cif_length[b] = wred[0] + wred[1] + wred[2] + wred[3];
}

// ---------------------------------------------------------------------------
// K3: gather/emit. Block = (k, b): output row k of batch b is
//   rem[e_{k-1}]*h[e_{k-1}] + sum_{t=e_{k-1}+1..e_k} cur[t]*h[t]
// Rows k >= n_fires[b] are zero (d_out is poisoned, must write).
// ---------------------------------------------------------------------------
__global__ __launch_bounds__(256) void k3_frames(
    const float* __restrict__ hidden, const float* __restrict__ cur,
    const float* __restrict__ rem, const int* __restrict__ fire_pos,
    const int* __restrict__ n_fires, float* __restrict__ out,
    int L, int Lpad)
{
    const int k = blockIdx.x;
    const int b = blockIdx.y;
    const int tid = threadIdx.x;
    const int h0 = tid * 4;
    float4 acc = make_float4(0.f, 0.f, 0.f, 0.f);
    const int n = n_fires[b];
    if (k < n) {
        const int e = fire_pos[b * Lpad + k];
        const int s = (k > 0) ? fire_pos[b * Lpad + k - 1] : -1;
        const size_t hb = ((size_t)b * T_) * H_ + h0;
        if (k > 0) {
            const float w = rem[(size_t)b * T_ + s];
            const float4 hr = *(const float4*)(hidden + hb + (size_t)s * H_);
            acc.x = w * hr.x; acc.y = w * hr.y; acc.z = w * hr.z; acc.w = w * hr.w;
        }
        for (int t = s + 1; t <= e; ++t) {
            const float w = cur[(size_t)b * T_ + t];
            const float4 hr = *(const float4*)(hidden + hb + (size_t)t * H_);
            acc.x = fmaf(w, hr.x, acc.x); acc.y = fmaf(w, hr.y, acc.y);
            acc.z = fmaf(w, hr.z, acc.z); acc.w = fmaf(w, hr.w, acc.w);
        }
    }
    *(float4*)(out + ((size_t)b * L + k) * H_ + h0) = acc;
}

extern "C" void kernel_launch(void* const* d_in, const int* in_sizes, int n_in,
                              void* d_out, int out_size, void* d_ws, size_t ws_size,
                              hipStream_t stream) {
    const float* hidden = (const float*)d_in[0];
    const float* conv_w = (const float*)d_in[1];
    const float* conv_b = (const float*)d_in[2];
    const float* lin_w  = (const float*)d_in[3];
    const float* lin_b  = (const float*)d_in[4];
    float* out = (float*)d_out;

    // out = [cif_output B*L*H | cif_length B | fires B*T]; L fixed per input set
    const int L = (out_size - B_ - B_ * T_) / (B_ * H_);
    float* cif_output = out;
    float* cif_length = out + (size_t)B_ * L * H_;
    float* fires      = cif_length + B_;

    // workspace: alphas, cur, rem (B*T floats each) + fire_pos + n_fires
    float* alphas = (float*)d_ws;
    float* cur    = alphas + (size_t)B_ * T_;
    float* rem    = cur + (size_t)B_ * T_;
    const int Lpad = L + 8;
    int* fire_pos = (int*)(rem + (size_t)B_ * T_);
    int* n_fires  = fire_pos + (size_t)B_ * Lpad;

    k1_alphas<<<dim3(B_ * (T_ / TPB)), 256, 0, stream>>>(
        hidden, conv_w, conv_b, lin_w, lin_b, alphas);
    k2a_scan<<<dim3(1), 64, 0, stream>>>(alphas, fires);
    k2b_coef<<<dim3(B_), 256, 0, stream>>>(
        alphas, fires, cur, rem, fire_pos, n_fires, cif_length, Lpad);
    k3_frames<<<dim3(L, B_), 256, 0, stream>>>(
        hidden, cur, rem, fire_pos, n_fires, cif_output, L, Lpad);
}

// Round 2
// 278.178 us; speedup vs baseline: 1.0643x; 1.0643x over previous
//
#include <hip/hip_runtime.h>
#include <math.h>

#define B_ 16
#define T_ 2048
#define H_ 1024
#define TPB 16  // t-rows per block in k1 (18/16 = 1.125x read overlap)

// ---------------------------------------------------------------------------
// K1: alphas[b,t] = sigmoid( sum_h relu(conv(h,t) + conv_b + hidden) * lin_w + lin_b )
// conv(h,t) = w0[h]*hidden[b,t-1,h] + w1[h]*hidden[b,t,h] + w2[h]*hidden[b,t+1,h]
// Block = 256 threads, each owns 4 h's (float4); processes TPB consecutive t
// with rolling prev/curr/next rows.
// ---------------------------------------------------------------------------
__global__ __launch_bounds__(256) void k1_alphas(
    const float* __restrict__ hidden, const float* __restrict__ conv_w,
    const float* __restrict__ conv_b, const float* __restrict__ lin_w,
    const float* __restrict__ lin_b, float* __restrict__ alphas)
{
    const int tile = blockIdx.x & (T_ / TPB - 1);
    const int b    = blockIdx.x / (T_ / TPB);
    const int tid  = threadIdx.x;
    const int h0   = tid * 4;

    // conv_w layout [H][1][3]: 12 consecutive floats per thread, 16B-aligned
    float w0[4], w1[4], w2[4];
    {
        const float4* cw = (const float4*)(conv_w + (size_t)h0 * 3);
        float4 c0 = cw[0], c1 = cw[1], c2 = cw[2];
        w0[0] = c0.x; w1[0] = c0.y; w2[0] = c0.z;
        w0[1] = c0.w; w1[1] = c1.x; w2[1] = c1.y;
        w0[2] = c1.z; w1[2] = c1.w; w2[2] = c2.x;
        w0[3] = c2.y; w1[3] = c2.z; w2[3] = c2.w;
    }
    const float4 cb = *(const float4*)(conv_b + h0);
    const float4 lw = *(const float4*)(lin_w + h0);
    const float  lb = lin_b[0];

    const size_t base = ((size_t)b * T_) * H_ + h0;
    const int t0 = tile * TPB;

    float4 prev = (t0 > 0) ? *(const float4*)(hidden + base + (size_t)(t0 - 1) * H_)
                           : make_float4(0.f, 0.f, 0.f, 0.f);
    float4 curr = *(const float4*)(hidden + base + (size_t)t0 * H_);
    float4 next;

    __shared__ float lds[4][TPB];
    const int wave = tid >> 6;
    const int lane = tid & 63;

    #pragma unroll
    for (int tt = 0; tt < TPB; ++tt) {
        const int t = t0 + tt;
        next = (t + 1 < T_) ? *(const float4*)(hidden + base + (size_t)(t + 1) * H_)
                            : make_float4(0.f, 0.f, 0.f, 0.f);
        float p = 0.f, v;
        v = fmaf(w0[0], prev.x, fmaf(w1[0], curr.x, fmaf(w2[0], next.x, cb.x + curr.x)));
        p = fmaf(fmaxf(v, 0.f), lw.x, p);
        v = fmaf(w0[1], prev.y, fmaf(w1[1], curr.y, fmaf(w2[1], next.y, cb.y + curr.y)));
        p = fmaf(fmaxf(v, 0.f), lw.y, p);
        v = fmaf(w0[2], prev.z, fmaf(w1[2], curr.z, fmaf(w2[2], next.z, cb.z + curr.z)));
        p = fmaf(fmaxf(v, 0.f), lw.z, p);
        v = fmaf(w0[3], prev.w, fmaf(w1[3], curr.w, fmaf(w2[3], next.w, cb.w + curr.w)));
        p = fmaf(fmaxf(v, 0.f), lw.w, p);
        // 64-lane wave reduce
        #pragma unroll
        for (int m = 32; m; m >>= 1) p += __shfl_xor(p, m);
        if (lane == 0) lds[wave][tt] = p;
        prev = curr; curr = next;
    }
    __syncthreads();
    if (tid < TPB) {
        float s = lds[0][tid] + lds[1][tid] + lds[2][tid] + lds[3][tid] + lb;
        alphas[(size_t)b * T_ + t0 + tid] = 1.f / (1.f + expf(-s));
    }
}

// ---------------------------------------------------------------------------
// K2a: minimal serial integrate-and-fire chain. One wave; lane = batch.
// fires[b,t] = I_{t-1} + alpha_t (pre-subtract).  I' = fract(I + a) is
// bit-exact vs the reference's conditional subtract: for x in [0,1) fract=x,
// for x in [1,2) fract(x) = x-1 exactly (Sterbenz).  Chain = add + fract.
// ---------------------------------------------------------------------------
__global__ __launch_bounds__(64) void k2a_scan(
    const float* __restrict__ alphas, float* __restrict__ fires)
{
    const int b = threadIdx.x;
    if (b >= B_) return;
    const float* a = alphas + (size_t)b * T_;
    float* f = fires + (size_t)b * T_;
    float I = 0.f;
    float4 c0 = *(const float4*)(a);
    float4 c1 = *(const float4*)(a + 4);
    float4 n0 = make_float4(0, 0, 0, 0), n1 = n0;
    for (int t = 0; t < T_; t += 8) {
        if (t + 8 < T_) {
            n0 = *(const float4*)(a + t + 8);
            n1 = *(const float4*)(a + t + 12);
        }
        float av[8] = {c0.x, c0.y, c0.z, c0.w, c1.x, c1.y, c1.z, c1.w};
        float fv[8];
        #pragma unroll
        for (int j = 0; j < 8; ++j) {
            I += av[j];
            fv[j] = I;
            I = __builtin_amdgcn_fractf(I);  // exact conditional -1 on [0,2)
        }
        *(float4*)(f + t)     = make_float4(fv[0], fv[1], fv[2], fv[3]);
        *(float4*)(f + t + 4) = make_float4(fv[4], fv[5], fv[6], fv[7]);
        c0 = n0; c1 = n1;
    }
}

// ---------------------------------------------------------------------------
// K2b: parallel reconstruction of per-t coefficients + fire positions.
// One block per batch, 256 threads x 8 t's. Also cif_length (sum of alphas).
// ---------------------------------------------------------------------------
__global__ __launch_bounds__(256) void k2b_coef(
    const float* __restrict__ alphas, const float* __restrict__ fires,
    float* __restrict__ cur, float* __restrict__ rem,
    int* __restrict__ fire_pos, int* __restrict__ n_fires,
    float* __restrict__ cif_length, int Lpad)
{
    const int b = blockIdx.x;
    const int tid = threadIdx.x;
    const int t0 = tid * 8;
    const size_t base = (size_t)b * T_;

    float a[8], f[8];
    *(float4*)(a)     = *(const float4*)(alphas + base + t0);
    *(float4*)(a + 4) = *(const float4*)(alphas + base + t0 + 4);
    *(float4*)(f)     = *(const float4*)(fires + base + t0);
    *(float4*)(f + 4) = *(const float4*)(fires + base + t0 + 4);
    const float fprev = (t0 == 0) ? 0.f : fires[base + t0 - 1];

    float cu[8], re[8];
    bool fr[8];
    float asum = 0.f;
    int cnt = 0;
    #pragma unroll
    for (int j = 0; j < 8; ++j) {
        float fp = (j == 0) ? fprev : f[j - 1];
        float Iprev = __builtin_amdgcn_fractf(fp);  // == (fp>=1)? fp-1 : fp
        fr[j] = (f[j] >= 1.f);
        const float dist = 1.f - Iprev;
        cu[j] = fr[j] ? dist : a[j];
        re[j] = a[j] - cu[j];
        cnt += fr[j] ? 1 : 0;
        asum += a[j];
    }
    *(float4*)(cur + base + t0)     = *(float4*)(cu);
    *(float4*)(cur + base + t0 + 4) = *(float4*)(cu + 4);
    *(float4*)(rem + base + t0)     = *(float4*)(re);
    *(float4*)(rem + base + t0 + 4) = *(float4*)(re + 4);

    // block-wide exclusive prefix of fire counts
    const int lane = tid & 63, wave = tid >> 6;
    int inc = cnt;
    #pragma unroll
    for (int d = 1; d < 64; d <<= 1) {
        int v = __shfl_up(inc, d);
        if (lane >= d) inc += v;
    }
    __shared__ int wsum[4];
    if (lane == 63) wsum[wave] = inc;
    __syncthreads();
    int waveoff = 0;
    for (int w = 0; w < wave; ++w) waveoff += wsum[w];
    int r = waveoff + inc - cnt;  // exclusive prefix for this thread
    #pragma unroll
    for (int j = 0; j < 8; ++j) {
        if (fr[j]) {
            if (r < Lpad) fire_pos[b * Lpad + r] = t0 + j;
            ++r;
        }
    }
    if (tid == 255) n_fires[b] = waveoff + inc;

    // cif_length = sum of alphas
    float s = asum;
    #pragma unroll
    for (int m = 32; m; m >>= 1) s += __shfl_xor(s, m);
    __shared__ float wred[4];
    if (lane == 0) wred[wave] = s;
    __syncthreads();
    if (tid == 0) cif_length[b] = wred[0] + wred[1] + wred[2] + wred[3];
}

// ---------------------------------------------------------------------------
// K3: gather/emit. Block = (k, b): output row k of batch b is
//   rem[e_{k-1}]*h[e_{k-1}] + sum_{t=e_{k-1}+1..e_k} cur[t]*h[t]
// Rows k >= n_fires[b] are zero (d_out is poisoned, must write).
// ---------------------------------------------------------------------------
__global__ __launch_bounds__(256) void k3_frames(
    const float* __restrict__ hidden, const float* __restrict__ cur,
    const float* __restrict__ rem, const int* __restrict__ fire_pos,
    const int* __restrict__ n_fires, float* __restrict__ out,
    int L, int Lpad)
{
    const int k = blockIdx.x;
    const int b = blockIdx.y;
    const int tid = threadIdx.x;
    const int h0 = tid * 4;
    float4 acc = make_float4(0.f, 0.f, 0.f, 0.f);
    const int n = n_fires[b];
    if (k < n) {
        const int e = fire_pos[b * Lpad + k];
        const int s = (k > 0) ? fire_pos[b * Lpad + k - 1] : -1;
        const size_t hb = ((size_t)b * T_) * H_ + h0;
        if (k > 0) {
            const float w = rem[(size_t)b * T_ + s];
            const float4 hr = *(const float4*)(hidden + hb + (size_t)s * H_);
            acc.x = w * hr.x; acc.y = w * hr.y; acc.z = w * hr.z; acc.w = w * hr.w;
        }
        for (int t = s + 1; t <= e; ++t) {
            const float w = cur[(size_t)b * T_ + t];
            const float4 hr = *(const float4*)(hidden + hb + (size_t)t * H_);
            acc.x = fmaf(w, hr.x, acc.x); acc.y = fmaf(w, hr.y, acc.y);
            acc.z = fmaf(w, hr.z, acc.z); acc.w = fmaf(w, hr.w, acc.w);
        }
    }
    *(float4*)(out + ((size_t)b * L + k) * H_ + h0) = acc;
}

extern "C" void kernel_launch(void* const* d_in, const int* in_sizes, int n_in,
                              void* d_out, int out_size, void* d_ws, size_t ws_size,
                              hipStream_t stream) {
    const float* hidden = (const float*)d_in[0];
    const float* conv_w = (const float*)d_in[1];
    const float* conv_b = (const float*)d_in[2];
    const float* lin_w  = (const float*)d_in[3];
    const float* lin_b  = (const float*)d_in[4];
    float* out = (float*)d_out;

    // out = [cif_output B*L*H | cif_length B | fires B*T]; L fixed per input set
    const int L = (out_size - B_ - B_ * T_) / (B_ * H_);
    float* cif_output = out;
    float* cif_length = out + (size_t)B_ * L * H_;
    float* fires      = cif_length + B_;

    // workspace: alphas, cur, rem (B*T floats each) + fire_pos + n_fires
    float* alphas = (float*)d_ws;
    float* cur    = alphas + (size_t)B_ * T_;
    float* rem    = cur + (size_t)B_ * T_;
    const int Lpad = L + 8;
    int* fire_pos = (int*)(rem + (size_t)B_ * T_);
    int* n_fires  = fire_pos + (size_t)B_ * Lpad;

    k1_alphas<<<dim3(B_ * (T_ / TPB)), 256, 0, stream>>>(
        hidden, conv_w, conv_b, lin_w, lin_b, alphas);
    k2a_scan<<<dim3(1), 64, 0, stream>>>(alphas, fires);
    k2b_coef<<<dim3(B_), 256, 0, stream>>>(
        alphas, fires, cur, rem, fire_pos, n_fires, cif_length, Lpad);
    k3_frames<<<dim3(L, B_), 256, 0, stream>>>(
        hidden, cur, rem, fire_pos, n_fires, cif_output, L, Lpad);
}

// Round 3
// 262.430 us; speedup vs baseline: 1.1281x; 1.0600x over previous
//
#include <hip/hip_runtime.h>
#include <math.h>

#define B_ 16
#define T_ 2048
#define H_ 1024
#define TPB 16  // t-rows per block in k1 (18/16 = 1.125x read overlap)
#define KPB 8   // output rows per block in k3

// ---------------------------------------------------------------------------
// K1: alphas[b,t] = sigmoid( sum_h relu(conv(h,t) + conv_b + hidden) * lin_w + lin_b )
// conv(h,t) = w0[h]*hidden[b,t-1,h] + w1[h]*hidden[b,t,h] + w2[h]*hidden[b,t+1,h]
// Block = 256 threads, each owns 4 h's (float4); TPB consecutive t with rolling
// prev/curr/next rows. TPB=16: 8 blocks/CU -> 32 waves/CU for latency hiding.
// ---------------------------------------------------------------------------
__global__ __launch_bounds__(256) void k1_alphas(
    const float* __restrict__ hidden, const float* __restrict__ conv_w,
    const float* __restrict__ conv_b, const float* __restrict__ lin_w,
    const float* __restrict__ lin_b, float* __restrict__ alphas)
{
    const int tile = blockIdx.x & (T_ / TPB - 1);
    const int b    = blockIdx.x / (T_ / TPB);
    const int tid  = threadIdx.x;
    const int h0   = tid * 4;

    // conv_w layout [H][1][3]: 12 consecutive floats per thread, 16B-aligned
    float w0[4], w1[4], w2[4];
    {
        const float4* cw = (const float4*)(conv_w + (size_t)h0 * 3);
        float4 c0 = cw[0], c1 = cw[1], c2 = cw[2];
        w0[0] = c0.x; w1[0] = c0.y; w2[0] = c0.z;
        w0[1] = c0.w; w1[1] = c1.x; w2[1] = c1.y;
        w0[2] = c1.z; w1[2] = c1.w; w2[2] = c2.x;
        w0[3] = c2.y; w1[3] = c2.z; w2[3] = c2.w;
    }
    const float4 cb = *(const float4*)(conv_b + h0);
    const float4 lw = *(const float4*)(lin_w + h0);
    const float  lb = lin_b[0];

    const size_t base = ((size_t)b * T_) * H_ + h0;
    const int t0 = tile * TPB;

    float4 prev = (t0 > 0) ? *(const float4*)(hidden + base + (size_t)(t0 - 1) * H_)
                           : make_float4(0.f, 0.f, 0.f, 0.f);
    float4 curr = *(const float4*)(hidden + base + (size_t)t0 * H_);
    float4 next;

    __shared__ float lds[4][TPB];
    const int wave = tid >> 6;
    const int lane = tid & 63;

    #pragma unroll
    for (int tt = 0; tt < TPB; ++tt) {
        const int t = t0 + tt;
        next = (t + 1 < T_) ? *(const float4*)(hidden + base + (size_t)(t + 1) * H_)
                            : make_float4(0.f, 0.f, 0.f, 0.f);
        float p = 0.f, v;
        v = fmaf(w0[0], prev.x, fmaf(w1[0], curr.x, fmaf(w2[0], next.x, cb.x + curr.x)));
        p = fmaf(fmaxf(v, 0.f), lw.x, p);
        v = fmaf(w0[1], prev.y, fmaf(w1[1], curr.y, fmaf(w2[1], next.y, cb.y + curr.y)));
        p = fmaf(fmaxf(v, 0.f), lw.y, p);
        v = fmaf(w0[2], prev.z, fmaf(w1[2], curr.z, fmaf(w2[2], next.z, cb.z + curr.z)));
        p = fmaf(fmaxf(v, 0.f), lw.z, p);
        v = fmaf(w0[3], prev.w, fmaf(w1[3], curr.w, fmaf(w2[3], next.w, cb.w + curr.w)));
        p = fmaf(fmaxf(v, 0.f), lw.w, p);
        // 64-lane wave reduce
        #pragma unroll
        for (int m = 32; m; m >>= 1) p += __shfl_xor(p, m);
        if (lane == 0) lds[wave][tt] = p;
        prev = curr; curr = next;
    }
    __syncthreads();
    if (tid < TPB) {
        float s = lds[0][tid] + lds[1][tid] + lds[2][tid] + lds[3][tid] + lb;
        alphas[(size_t)b * T_ + t0 + tid] = 1.f / (1.f + expf(-s));
    }
}

// ---------------------------------------------------------------------------
// K2 (fused scan+coef): one block per batch.
// Phase 1: cooperative load alphas[b,:] -> LDS.
// Phase 2: thread 0 runs the serial integrate-and-fire chain in LDS.
//   I' = fract(I + a) is bit-exact vs the reference's conditional subtract
//   (fract(x)=x on [0,1); fract(x)=x-1 exactly on [1,2) by Sterbenz).
// Phase 3: all 256 threads reconstruct cur/rem/fire_pos/n_fires/cif_length and
//   write fires coalesced.
// ---------------------------------------------------------------------------
__global__ __launch_bounds__(256) void k2_scan_coef(
    const float* __restrict__ alphas, float* __restrict__ fires,
    float* __restrict__ cur, float* __restrict__ rem,
    int* __restrict__ fire_pos, int* __restrict__ n_fires,
    float* __restrict__ cif_length, int Lpad)
{
    const int b = blockIdx.x;
    const int tid = threadIdx.x;
    const size_t base = (size_t)b * T_;

    __shared__ float sA[T_];  // 8 KB
    __shared__ float sF[T_];  // 8 KB

    // Phase 1: stage alphas
    {
        const int i = tid * 8;  // 256*8 = 2048 = T_
        *(float4*)(sA + i)     = *(const float4*)(alphas + base + i);
        *(float4*)(sA + i + 4) = *(const float4*)(alphas + base + i + 4);
    }
    __syncthreads();

    // Phase 2: serial scan (thread 0)
    if (tid == 0) {
        float I = 0.f;
        for (int t = 0; t < T_; t += 8) {
            #pragma unroll
            for (int j = 0; j < 8; ++j) {
                I += sA[t + j];
                sF[t + j] = I;
                I = __builtin_amdgcn_fractf(I);  // exact conditional -1 on [0,2)
            }
        }
    }
    __syncthreads();

    // Phase 3: coefficients + fire positions + outputs
    const int t0 = tid * 8;
    float a[8], f[8];
    #pragma unroll
    for (int j = 0; j < 8; ++j) { a[j] = sA[t0 + j]; f[j] = sF[t0 + j]; }
    const float fprev = (t0 == 0) ? 0.f : sF[t0 - 1];

    // fires output (coalesced)
    *(float4*)(fires + base + t0)     = make_float4(f[0], f[1], f[2], f[3]);
    *(float4*)(fires + base + t0 + 4) = make_float4(f[4], f[5], f[6], f[7]);

    float cu[8], re[8];
    bool fr[8];
    float asum = 0.f;
    int cnt = 0;
    #pragma unroll
    for (int j = 0; j < 8; ++j) {
        float fp = (j == 0) ? fprev : f[j - 1];
        float Iprev = __builtin_amdgcn_fractf(fp);  // == (fp>=1)? fp-1 : fp
        fr[j] = (f[j] >= 1.f);
        const float dist = 1.f - Iprev;
        cu[j] = fr[j] ? dist : a[j];
        re[j] = a[j] - cu[j];
        cnt += fr[j] ? 1 : 0;
        asum += a[j];
    }
    *(float4*)(cur + base + t0)     = *(float4*)(cu);
    *(float4*)(cur + base + t0 + 4) = *(float4*)(cu + 4);
    *(float4*)(rem + base + t0)     = *(float4*)(re);
    *(float4*)(rem + base + t0 + 4) = *(float4*)(re + 4);

    // block-wide exclusive prefix of fire counts
    const int lane = tid & 63, wave = tid >> 6;
    int inc = cnt;
    #pragma unroll
    for (int d = 1; d < 64; d <<= 1) {
        int v = __shfl_up(inc, d);
        if (lane >= d) inc += v;
    }
    __shared__ int wsum[4];
    if (lane == 63) wsum[wave] = inc;
    __syncthreads();
    int waveoff = 0;
    for (int w = 0; w < wave; ++w) waveoff += wsum[w];
    int r = waveoff + inc - cnt;  // exclusive prefix for this thread
    #pragma unroll
    for (int j = 0; j < 8; ++j) {
        if (fr[j]) {
            if (r < Lpad) fire_pos[b * Lpad + r] = t0 + j;
            ++r;
        }
    }
    if (tid == 255) n_fires[b] = waveoff + inc;

    // cif_length = sum of alphas
    float s = asum;
    #pragma unroll
    for (int m = 32; m; m >>= 1) s += __shfl_xor(s, m);
    __shared__ float wred[4];
    if (lane == 0) wred[wave] = s;
    __syncthreads();
    if (tid == 0) cif_length[b] = wred[0] + wred[1] + wred[2] + wred[3];
}

// ---------------------------------------------------------------------------
// K3: gather/emit, KPB output rows per block. Row k of batch b is
//   rem[e_{k-1}]*h[e_{k-1}] + sum_{t=e_{k-1}+1..e_k} cur[t]*h[t]
// Carrying the segment-end row in registers across the KPB rows removes the
// per-k boundary re-read (~30% of k3 traffic). Rows k >= n_fires[b] are zero
// (d_out is poisoned, must write).
// ---------------------------------------------------------------------------
__global__ __launch_bounds__(256) void k3_frames(
    const float* __restrict__ hidden, const float* __restrict__ cur,
    const float* __restrict__ rem, const int* __restrict__ fire_pos,
    const int* __restrict__ n_fires, float* __restrict__ out,
    int L, int Lpad)
{
    const int k0 = blockIdx.x * KPB;
    const int b  = blockIdx.y;
    const int tid = threadIdx.x;
    const int h0 = tid * 4;
    const int n = n_fires[b];
    const size_t hb = ((size_t)b * T_) * H_ + h0;
    const size_t cb = (size_t)b * T_;

    int s = -1;
    float4 hprev = make_float4(0.f, 0.f, 0.f, 0.f);
    if (k0 > 0) {
        s = fire_pos[b * Lpad + k0 - 1];  // valid whenever k0-1 < n (else unused)
        if (k0 < n)
            hprev = *(const float4*)(hidden + hb + (size_t)s * H_);
    }

    #pragma unroll 1
    for (int kk = 0; kk < KPB; ++kk) {
        const int k = k0 + kk;
        if (k >= L) break;  // uniform
        float4 acc = make_float4(0.f, 0.f, 0.f, 0.f);
        if (k < n) {
            const int e = fire_pos[b * Lpad + k];
            if (k > 0) {
                const float w = rem[cb + s];
                acc.x = w * hprev.x; acc.y = w * hprev.y;
                acc.z = w * hprev.z; acc.w = w * hprev.w;
            }
            for (int t = s + 1; t < e; ++t) {
                const float w = cur[cb + t];
                const float4 hr = *(const float4*)(hidden + hb + (size_t)t * H_);
                acc.x = fmaf(w, hr.x, acc.x); acc.y = fmaf(w, hr.y, acc.y);
                acc.z = fmaf(w, hr.z, acc.z); acc.w = fmaf(w, hr.w, acc.w);
            }
            // t = e: load once, keep for next k's rem term
            {
                const float w = cur[cb + e];
                const float4 hr = *(const float4*)(hidden + hb + (size_t)e * H_);
                acc.x = fmaf(w, hr.x, acc.x); acc.y = fmaf(w, hr.y, acc.y);
                acc.z = fmaf(w, hr.z, acc.z); acc.w = fmaf(w, hr.w, acc.w);
                hprev = hr;
            }
            s = e;
        }
        *(float4*)(out + ((size_t)b * L + k) * H_ + h0) = acc;
    }
}

extern "C" void kernel_launch(void* const* d_in, const int* in_sizes, int n_in,
                              void* d_out, int out_size, void* d_ws, size_t ws_size,
                              hipStream_t stream) {
    const float* hidden = (const float*)d_in[0];
    const float* conv_w = (const float*)d_in[1];
    const float* conv_b = (const float*)d_in[2];
    const float* lin_w  = (const float*)d_in[3];
    const float* lin_b  = (const float*)d_in[4];
    float* out = (float*)d_out;

    // out = [cif_output B*L*H | cif_length B | fires B*T]; L fixed per input set
    const int L = (out_size - B_ - B_ * T_) / (B_ * H_);
    float* cif_output = out;
    float* cif_length = out + (size_t)B_ * L * H_;
    float* fires      = cif_length + B_;

    // workspace: alphas, cur, rem (B*T floats each) + fire_pos + n_fires
    float* alphas = (float*)d_ws;
    float* cur    = alphas + (size_t)B_ * T_;
    float* rem    = cur + (size_t)B_ * T_;
    const int Lpad = L + 8;
    int* fire_pos = (int*)(rem + (size_t)B_ * T_);
    int* n_fires  = fire_pos + (size_t)B_ * Lpad;

    k1_alphas<<<dim3(B_ * (T_ / TPB)), 256, 0, stream>>>(
        hidden, conv_w, conv_b, lin_w, lin_b, alphas);
    k2_scan_coef<<<dim3(B_), 256, 0, stream>>>(
        alphas, fires, cur, rem, fire_pos, n_fires, cif_length, Lpad);
    k3_frames<<<dim3((L + KPB - 1) / KPB, B_), 256, 0, stream>>>(
        hidden, cur, rem, fire_pos, n_fires, cif_output, L, Lpad);
}